// Round 1
// baseline (105.679 us; speedup 1.0000x reference)
//
#include <hip/hip_runtime.h>
#include <math.h>

// Problem constants (from reference setup_inputs)
#define B     16
#define PDIM  2048
#define QDIM  2048

// Tiling for the fused weights pass
#define QTILE  128   // threads per block, one q per thread
#define PCHUNK 64    // p rows per block
#define NQB (QDIM / QTILE)   // 16
#define NPC (PDIM / PCHUNK)  // 32

// Fused pass over weights [P,Q]:
//   - new_weights[p,q] = clamp(weights[p,q], 0, 1)
//     (weight_changes is identically 0 — see launch comment — so the
//      multiplicative soft-bound update is the identity + clip)
//   - synaptic_current[b,q] += sum over spiking p of weights[p,q]
//     (pre_spikes are exactly {0.0,1.0}; matmul == masked column sum)
// Spike occupancy per p is packed into a 16-bit mask, read through
// readfirstlane so the per-batch accumulate compiles to scalar-branch-guarded
// v_add (SGPR condition, ~95% of branches skipped).
__global__ __launch_bounds__(QTILE) void stdp_main(
    const float* __restrict__ pre_spikes,  // [B, P]
    const float* __restrict__ weights,     // [P, Q]
    float* __restrict__ sc,                // [B, Q], pre-zeroed
    float* __restrict__ nw)                // [P, Q]
{
    __shared__ unsigned smask[PCHUNK];

    const int qb = blockIdx.x & (NQB - 1);
    const int pc = blockIdx.x >> 4;        // NQB == 16
    const int q  = qb * QTILE + threadIdx.x;
    const int p0 = pc * PCHUNK;

    // Build the per-p spike bitmask for this chunk (threads 0..63)
    if (threadIdx.x < PCHUNK) {
        const int p = p0 + threadIdx.x;
        unsigned m = 0;
        #pragma unroll
        for (int b = 0; b < B; ++b)
            m |= (pre_spikes[b * PDIM + p] > 0.0f) ? (1u << b) : 0u;
        smask[threadIdx.x] = m;
    }
    __syncthreads();

    float acc[B];
    #pragma unroll
    for (int b = 0; b < B; ++b) acc[b] = 0.0f;

    const float* __restrict__ wptr  = weights + (size_t)p0 * QDIM + q;
    float* __restrict__       nwptr = nw      + (size_t)p0 * QDIM + q;

    #pragma unroll 8
    for (int i = 0; i < PCHUNK; ++i) {
        float w = wptr[(size_t)i * QDIM];                       // coalesced 4B/lane
        nwptr[(size_t)i * QDIM] = fminf(fmaxf(w, 0.0f), 1.0f);  // new_weights
        unsigned m = (unsigned)__builtin_amdgcn_readfirstlane((int)smask[i]);
        #pragma unroll
        for (int b = 0; b < B; ++b)
            if (m & (1u << b)) acc[b] += w;   // scalar-branch guarded
    }

    // 32 partial contributions per (b,q) across p-chunks → device-scope atomics
    #pragma unroll
    for (int b = 0; b < B; ++b)
        atomicAdd(&sc[b * QDIM + q], acc[b]);
}

// Trace decay + spike accumulation; both pre [B,P] and post [B,Q] handled
// by one thread each (32768 threads).
__global__ __launch_bounds__(256) void stdp_traces(
    const float* __restrict__ pre_s,
    const float* __restrict__ post_s,
    const float* __restrict__ pre_t,
    const float* __restrict__ post_t,
    const float* __restrict__ dtp,      // scalar dt on device
    float* __restrict__ pre_o,
    float* __restrict__ post_o)
{
    const int i = blockIdx.x * blockDim.x + threadIdx.x;   // < B*PDIM == B*QDIM
    const float decay = expf(-dtp[0] / 0.02f);             // TAU_PLUS == TAU_MINUS
    pre_o[i]  = pre_t[i]  * decay + pre_s[i];
    post_o[i] = post_t[i] * decay + post_s[i];
}

extern "C" void kernel_launch(void* const* d_in, const int* in_sizes, int n_in,
                              void* d_out, int out_size, void* d_ws, size_t ws_size,
                              hipStream_t stream) {
    // Input order (setup_inputs dict): pre_spikes, post_spikes, weights,
    // pre_trace, post_trace, last_pre_spike, last_post_spike, current_time, dt
    const float* pre_spikes  = (const float*)d_in[0];
    const float* post_spikes = (const float*)d_in[1];
    const float* weights     = (const float*)d_in[2];
    const float* pre_trace   = (const float*)d_in[3];
    const float* post_trace  = (const float*)d_in[4];
    // last_pre_spike / last_post_spike / current_time are provably unused:
    // active pairs require BOTH neurons to spike at current_time, forcing
    // dts = current_time - current_time = 0, which satisfies neither
    // (dts > 0) nor (dts < 0) → weight_changes ≡ 0 identically.
    const float* dtp         = (const float*)d_in[8];

    // Output layout (flat, return order):
    //   synaptic_current [B,Q]   : 32768
    //   weight_changes   [P,Q]   : 4194304   (== 0)
    //   pre_trace_new    [B,P]   : 32768
    //   post_trace_new   [B,Q]   : 32768
    //   new_weights      [P,Q]   : 4194304
    float* out    = (float*)d_out;
    float* sc     = out;
    float* wc     = out + (size_t)B * QDIM;
    float* pre_o  = wc  + (size_t)PDIM * QDIM;
    float* post_o = pre_o + (size_t)B * PDIM;
    float* nw     = post_o + (size_t)B * QDIM;

    // sc and wc are adjacent: one memset zeroes both (sc is the atomic
    // accumulator base; wc is the final answer — identically zero).
    hipMemsetAsync(sc, 0, ((size_t)B * QDIM + (size_t)PDIM * QDIM) * sizeof(float),
                   stream);

    stdp_main<<<dim3(NQB * NPC), dim3(QTILE), 0, stream>>>(
        pre_spikes, weights, sc, nw);

    stdp_traces<<<dim3((B * PDIM) / 256), dim3(256), 0, stream>>>(
        pre_spikes, post_spikes, pre_trace, post_trace, dtp, pre_o, post_o);
}

// Round 2
// 101.939 us; speedup vs baseline: 1.0367x; 1.0367x over previous
//
#include <hip/hip_runtime.h>
#include <math.h>

// Problem constants (from reference setup_inputs)
#define B     16
#define PDIM  2048
#define QDIM  2048

// stdp_main tiling: block = 256 threads = 4 waves.
//  - wave w owns batches b in [4w, 4w+4)          (b-split: no cross-thread b reduction)
//  - lane l owns 4 consecutive q (float4)          -> block covers 256 q
//  - block processes PCHUNK rows of W
// Grid = NQB * NPC = 8 * 64 = 512 blocks = 2048 waves (2 waves/SIMD resident).
#define NQB    8      // Q / 256
#define NPC    64     // P / PCHUNK
#define PCHUNK 32

// weight_changes is identically 0: an active STDP pair requires BOTH neurons
// to spike at current_time, forcing dts = 0, which satisfies neither
// (dts > 0) nor (dts < 0). So new_weights = clamp(weights, 0, 1) and the
// whole B*P*Q tensor never needs to exist. The kernel is a streaming pass
// over W: read 16.8 MB, write nw (16.8) + wc zeros (16.8) + sc partials (8.4).
__global__ __launch_bounds__(256) void stdp_main(
    const float* __restrict__ pre_spikes,  // [B, P], values exactly {0.0, 1.0}
    const float* __restrict__ weights,     // [P, Q]
    float* __restrict__ nw,                // [P, Q]  clamp(W)
    float* __restrict__ wc,                // [P, Q]  zeros
    float* __restrict__ ws)                // [NPC, B, Q] partial column sums
{
    __shared__ float sp[PCHUNK][B];        // spikes, [p_local][b], 2 KB

    const int qb   = blockIdx.x & (NQB - 1);
    const int pc   = blockIdx.x >> 3;
    const int p0   = pc * PCHUNK;
    const int wave = threadIdx.x >> 6;     // 0..3
    const int lane = threadIdx.x & 63;
    const int q    = qb * 256 + lane * 4;
    const int b0   = wave * 4;

    // Stage this chunk's spike values (512 floats), coalesced in 32-lane runs.
    for (int t = threadIdx.x; t < B * PCHUNK; t += 256) {
        const int b  = t >> 5;             // PCHUNK == 32
        const int pl = t & (PCHUNK - 1);
        sp[pl][b] = pre_spikes[b * PDIM + p0 + pl];
    }
    __syncthreads();

    float4 acc0 = {0,0,0,0}, acc1 = {0,0,0,0}, acc2 = {0,0,0,0}, acc3 = {0,0,0,0};

    const size_t base = (size_t)p0 * QDIM + q;
    const float* __restrict__ wp  = weights + base;
    float* __restrict__       nwp = nw + base;
    float* __restrict__       wcp = wc + base;

    #pragma unroll 8
    for (int i = 0; i < PCHUNK; ++i) {
        const float4 w = *(const float4*)(wp + (size_t)i * QDIM);   // 16 B/lane, coalesced
        // wave-uniform ds_read_b128 -> broadcast, conflict-free
        const float4 s = *(const float4*)&sp[i][b0];

        acc0.x = fmaf(s.x, w.x, acc0.x); acc0.y = fmaf(s.x, w.y, acc0.y);
        acc0.z = fmaf(s.x, w.z, acc0.z); acc0.w = fmaf(s.x, w.w, acc0.w);
        acc1.x = fmaf(s.y, w.x, acc1.x); acc1.y = fmaf(s.y, w.y, acc1.y);
        acc1.z = fmaf(s.y, w.z, acc1.z); acc1.w = fmaf(s.y, w.w, acc1.w);
        acc2.x = fmaf(s.z, w.x, acc2.x); acc2.y = fmaf(s.z, w.y, acc2.y);
        acc2.z = fmaf(s.z, w.z, acc2.z); acc2.w = fmaf(s.z, w.w, acc2.w);
        acc3.x = fmaf(s.w, w.x, acc3.x); acc3.y = fmaf(s.w, w.y, acc3.y);
        acc3.z = fmaf(s.w, w.z, acc3.z); acc3.w = fmaf(s.w, w.w, acc3.w);

        if (wave == 0) {                   // wave-uniform branch (s_cbranch)
            float4 c;
            c.x = fminf(fmaxf(w.x, 0.0f), 1.0f);
            c.y = fminf(fmaxf(w.y, 0.0f), 1.0f);
            c.z = fminf(fmaxf(w.z, 0.0f), 1.0f);
            c.w = fminf(fmaxf(w.w, 0.0f), 1.0f);
            *(float4*)(nwp + (size_t)i * QDIM) = c;
        } else if (wave == 1) {
            const float4 z = {0,0,0,0};
            *(float4*)(wcp + (size_t)i * QDIM) = z;
        }
    }

    // Partial column sums: ws[pc][b][q], one writer per element (no atomics,
    // no pre-zero needed -> poison-safe).
    float* __restrict__ wsp = ws + ((size_t)(pc * B + b0)) * QDIM + q;
    *(float4*)(wsp + 0 * (size_t)QDIM) = acc0;
    *(float4*)(wsp + 1 * (size_t)QDIM) = acc1;
    *(float4*)(wsp + 2 * (size_t)QDIM) = acc2;
    *(float4*)(wsp + 3 * (size_t)QDIM) = acc3;
}

// Tail: trace decay for pre [B,P] and post [B,Q] (one thread each of 32768),
// fused with the sc reduction over the NPC partial slabs (threads 0..8191,
// float4 per thread). Runs after stdp_main in stream order.
__global__ __launch_bounds__(256) void stdp_tail(
    const float* __restrict__ pre_s,
    const float* __restrict__ post_s,
    const float* __restrict__ pre_t,
    const float* __restrict__ post_t,
    const float* __restrict__ dtp,      // scalar dt on device
    const float* __restrict__ ws,       // [NPC, B, Q]
    float* __restrict__ pre_o,
    float* __restrict__ post_o,
    float* __restrict__ sc)             // [B, Q]
{
    const int i = blockIdx.x * blockDim.x + threadIdx.x;   // < 32768
    const float decay = expf(-dtp[0] * 50.0f);             // 1/TAU == 50
    pre_o[i]  = pre_t[i]  * decay + pre_s[i];
    post_o[i] = post_t[i] * decay + post_s[i];

    if (i < (B * QDIM) / 4) {
        const int b  = i >> 9;                 // QDIM/4 == 512
        const int qc = (i & 511) << 2;
        const float* __restrict__ p = ws + (size_t)b * QDIM + qc;
        float4 s = {0,0,0,0};
        #pragma unroll 8
        for (int pc = 0; pc < NPC; ++pc) {
            const float4 v = *(const float4*)(p + (size_t)pc * B * QDIM);
            s.x += v.x; s.y += v.y; s.z += v.z; s.w += v.w;
        }
        *(float4*)(sc + (size_t)b * QDIM + qc) = s;
    }
}

extern "C" void kernel_launch(void* const* d_in, const int* in_sizes, int n_in,
                              void* d_out, int out_size, void* d_ws, size_t ws_size,
                              hipStream_t stream) {
    // Input order: pre_spikes, post_spikes, weights, pre_trace, post_trace,
    // last_pre_spike, last_post_spike, current_time, dt
    // (last_*_spike / current_time provably unused — see stdp_main comment)
    const float* pre_spikes  = (const float*)d_in[0];
    const float* post_spikes = (const float*)d_in[1];
    const float* weights     = (const float*)d_in[2];
    const float* pre_trace   = (const float*)d_in[3];
    const float* post_trace  = (const float*)d_in[4];
    const float* dtp         = (const float*)d_in[8];

    // Output layout (flat, return order):
    //   synaptic_current [B,Q], weight_changes [P,Q] (==0),
    //   pre_trace_new [B,P], post_trace_new [B,Q], new_weights [P,Q]
    float* out    = (float*)d_out;
    float* sc     = out;
    float* wc     = out + (size_t)B * QDIM;
    float* pre_o  = wc  + (size_t)PDIM * QDIM;
    float* post_o = pre_o + (size_t)B * PDIM;
    float* nw     = post_o + (size_t)B * QDIM;

    float* ws = (float*)d_ws;   // NPC*B*Q*4 = 8.4 MB, fully overwritten before read

    stdp_main<<<dim3(NQB * NPC), dim3(256), 0, stream>>>(
        pre_spikes, weights, nw, wc, ws);

    stdp_tail<<<dim3((B * PDIM) / 256), dim3(256), 0, stream>>>(
        pre_spikes, post_spikes, pre_trace, post_trace, dtp, ws, pre_o, post_o, sc);
}